// Round 12
// baseline (133.305 us; speedup 1.0000x reference)
//
#include <hip/hip_runtime.h>
#include <stdint.h>

// Sampler_6107443495068 — vLLM-style sampler on MI355X (gfx950).
// R15 post-mortem: rank sort real win (-6 µs, kernel ~38, total 130 best).
//   RETRACTION: R2 "L3-warm null" was a counter artifact (FETCH=NaN pass;
//   hbm_bytes was WRITE-only). Corrected model: delivered BW ~ 0.8 GB/s
//   per wave (m13: 6.3 TB/s at 8192 waves; ours: 1024 waves -> 790 GB/s
//   measured). Stream IS the kernel (33 MB / 0.79 TB/s = 42 µs). Depth/
//   spill/per-wave knobs null because only TOTAL WAVES matters. Fused
//   1-block/row caps at 2048 waves -> floor ~35-40. Split is the only path.
// R16: minimal-overhead split. K1: 16 blk/row = 2048 blocks
//   (8192 waves, full machine) -> ~6 TB/s, ~12 µs; per-block private
//   count/sum/candidate segments => NO atomics, NO memset dispatch.
//   K2: R10-verified rank-sort finalize (order-canonicalizing => segment
//   gather order irrelevant, deterministic). 2 dispatches total.
// R17 (this round): identical resubmit — R16 bench died on container
//   acquisition (infra); the wave-count-law test never ran.
//   Predict: K1 10-14 µs @ 4.5-6.5 TB/s, K2 8-14 µs, total 112-122.
// RNG: exact JAX threefry2x32 partitionable (bits = x0^x1), key 42.

#define NTA      256                 // K1 threads
#define SLOTS_K1 8                   // float4 per K1 thread
#define CHUNK4   (NTA * SLOTS_K1)    // 2048 float4 per block
#define CAPB     128                 // per-block candidate segment cap
#define NBLKMAX  32                  // segment slots per row in ws
#define NTB      512                 // K2 threads
#define GCAP     1024                // per-row candidate cap in K2
#define BITWORDS 4000                // 128000 / 32
#define HASHSZ   1024
#define CUTF     3.0f                // candidate cutoff (== fkey 0xC0400000)
#define HASH_EMPTY 0xFFFFFFFFu
#define NEG_INF_F -3.402823466e38f   // jnp.finfo(f32).min
#define PADV     -1.0e30f

__device__ __forceinline__ uint32_t fkey(float f) {
  uint32_t u = __float_as_uint(f);
  return (u & 0x80000000u) ? ~u : (u | 0x80000000u);
}
__device__ __forceinline__ float funkey(uint32_t k) {
  uint32_t u = (k & 0x80000000u) ? (k & 0x7FFFFFFFu) : ~k;
  return __uint_as_float(u);
}

__device__ __forceinline__ void threefry(uint32_t x0, uint32_t x1,
                                         uint32_t &o0, uint32_t &o1) {
  const uint32_t ks0 = 0u, ks1 = 42u, ks2 = 0u ^ 42u ^ 0x1BD11BDAu;
  x0 += ks0; x1 += ks1;
#define TF_R(r) { x0 += x1; x1 = (x1 << (r)) | (x1 >> (32 - (r))); x1 ^= x0; }
  TF_R(13) TF_R(15) TF_R(26) TF_R(6)
  x0 += ks1; x1 += ks2 + 1u;
  TF_R(17) TF_R(29) TF_R(16) TF_R(24)
  x0 += ks2; x1 += ks0 + 2u;
  TF_R(13) TF_R(15) TF_R(26) TF_R(6)
  x0 += ks0; x1 += ks1 + 3u;
  TF_R(17) TF_R(29) TF_R(16) TF_R(24)
  x0 += ks1; x1 += ks2 + 4u;
  TF_R(13) TF_R(15) TF_R(26) TF_R(6)
  x0 += ks2; x1 += ks0 + 5u;
#undef TF_R
  o0 = x0; o1 = x1;
}

__device__ __forceinline__ float gumbel_at(uint64_t flat) {
  uint32_t o0, o1;
  threefry((uint32_t)(flat >> 32), (uint32_t)flat, o0, o1);
  uint32_t bits = o0 ^ o1;
  float f = __uint_as_float((bits >> 9) | 0x3F800000u) - 1.0f;  // [0,1)
  float u = fmaxf(1e-10f, f + 1e-10f);
  return -logf(-logf(u));
}

// ---------------- K1: stream logits (full-machine wave count) -------------
template<int CNV4>
__global__ __launch_bounds__(NTA)
__attribute__((amdgpu_waves_per_eu(4, 4)))   // 128 VGPR budget, no spill
void stream_kernel(const float* __restrict__ logits,
                   uint32_t* __restrict__ ws_cntp,
                   float* __restrict__ ws_sump,
                   uint64_t* __restrict__ ws_cand,
                   int V, int nv4_arg)
{
  const int row = blockIdx.y;
  const int bx  = blockIdx.x;
  const int nv4 = (CNV4 > 0) ? CNV4 : nv4_arg;
  const int i0 = bx * CHUNK4 + threadIdx.x;
  const int t = threadIdx.x;
  const float4* lg4 = (const float4*)(logits + (size_t)row * V);

  __shared__ uint64_t sh_buf[CAPB];
  __shared__ uint32_t sh_cnt;
  __shared__ float    sh_ws[NTA / 64];
  if (t == 0) sh_cnt = 0u;
  __syncthreads();

  auto ld = [&](int slot) -> float4 {
    int idx = i0 + slot * NTA;
    return (idx < nv4) ? lg4[idx] : make_float4(PADV, PADV, PADV, PADV);
  };

  // issue all 8 loads up front (8-deep), then consume
  float4 buf[SLOTS_K1];
#pragma unroll
  for (int s = 0; s < SLOTS_K1; s++) buf[s] = ld(s);

  float sa = 0.f, sb = 0.f, sc = 0.f, sd = 0.f;
#pragma unroll
  for (int s = 0; s < SLOTS_K1; s++) {
    float4 f = buf[s];
    sa += __expf(f.x); sb += __expf(f.y);
    sc += __expf(f.z); sd += __expf(f.w);
    bool c0 = f.x >= CUTF, c1 = f.y >= CUTF, c2 = f.z >= CUTF, c3 = f.w >= CUTF;
    if (__any(c0 | c1 | c2 | c3)) {
      int vb = (i0 + s * NTA) << 2;
      if (c0) { uint32_t sl = atomicAdd(&sh_cnt, 1u); if (sl < CAPB) sh_buf[sl] = ((uint64_t)fkey(f.x) << 32) | (uint32_t)(~(uint32_t)(vb + 0)); }
      if (c1) { uint32_t sl = atomicAdd(&sh_cnt, 1u); if (sl < CAPB) sh_buf[sl] = ((uint64_t)fkey(f.y) << 32) | (uint32_t)(~(uint32_t)(vb + 1)); }
      if (c2) { uint32_t sl = atomicAdd(&sh_cnt, 1u); if (sl < CAPB) sh_buf[sl] = ((uint64_t)fkey(f.z) << 32) | (uint32_t)(~(uint32_t)(vb + 2)); }
      if (c3) { uint32_t sl = atomicAdd(&sh_cnt, 1u); if (sl < CAPB) sh_buf[sl] = ((uint64_t)fkey(f.w) << 32) | (uint32_t)(~(uint32_t)(vb + 3)); }
    }
  }

  // block exp-sum (deterministic order)
  float s = (sa + sb) + (sc + sd);
  for (int off = 1; off < 64; off <<= 1) s += __shfl_xor(s, off);
  if ((t & 63) == 0) sh_ws[t >> 6] = s;
  __syncthreads();

  if (t == 0) {
    float tt = 0.f;
    for (int w = 0; w < NTA / 64; w++) tt += sh_ws[w];
    ws_sump[(size_t)row * NBLKMAX + bx] = tt;       // private slot, no atomic
    uint32_t cnt = (sh_cnt < CAPB) ? sh_cnt : CAPB;
    ws_cntp[(size_t)row * NBLKMAX + bx] = cnt;      // private slot, no atomic
  }
  __syncthreads();

  // flush candidates to private segment (coalesced)
  uint32_t cnt = (sh_cnt < CAPB) ? sh_cnt : CAPB;
  uint64_t segbase = (size_t)row * (NBLKMAX * CAPB) + (size_t)bx * CAPB;
  for (uint32_t i = t; i < cnt; i += NTA)
    ws_cand[segbase + i] = sh_buf[i];
}

// ---------------- K2: finalize per row (rank sort, R10-verified) ----------
__global__ __launch_bounds__(NTB)
__attribute__((amdgpu_waves_per_eu(2, 2)))
void finalize_kernel(const float* __restrict__ temperature,
                     const float* __restrict__ presence,
                     const float* __restrict__ frequency,
                     const float* __restrict__ repetition,
                     const float* __restrict__ top_p,
                     const int* __restrict__ prompt_ids,
                     const int* __restrict__ output_ids,
                     const int* __restrict__ output_lens,
                     const int* __restrict__ stop_ids,
                     const int* __restrict__ min_tokens,
                     const int* __restrict__ top_k,
                     const uint32_t* __restrict__ ws_cntp,
                     const float* __restrict__ ws_sump,
                     const uint64_t* __restrict__ ws_cand,
                     float* __restrict__ out,
                     int B, int V, int P, int O, int S, int NL, int nblk)
{
  __shared__ uint32_t sh_bitmap[BITWORDS];   // 16000 B
  __shared__ uint32_t sh_hash[HASHSZ];       //  4096 B
  __shared__ uint64_t sh_cand[GCAP];         //  8192 B (unsorted raw)
  __shared__ uint64_t sh_sort[GCAP];         //  8192 B (unsorted penalized)
  __shared__ uint64_t sh_cand_s[GCAP];       //  8192 B (rank-sorted raw)
  __shared__ uint64_t sh_sort_s[GCAP];       //  8192 B (rank-sorted penalized)
  __shared__ float    sh_eval[GCAP];         //  4096 B
  __shared__ float    sh_redm[NTB / 64];
  __shared__ int      sh_redi[NTB / 64];
  __shared__ int      sh_off[NBLKMAX + 1];
  __shared__ int      sh_s, sh_cut;

  const int row = blockIdx.x;
  const int tid = threadIdx.x;

  const float temp = temperature[row];
  const float pres = presence[row];
  const float freq = frequency[row];
  const float rep  = repetition[row];
  const float topp = top_p[row];
  const int   olen = output_lens[row];
  const int   mint = min_tokens[row];
  int k = top_k[row]; if (k < 1) k = 1; if (k > V) k = V;
  const bool  penal = olen < mint;
  const int   s0 = stop_ids[row*S + 0], s1 = stop_ids[row*S + 1];
  const int   s2 = stop_ids[row*S + 2], s3 = stop_ids[row*S + 3];
  const float temp_eff = (temp < 1e-5f) ? 1.0f : temp;

  float tsum = 0.f;
  for (int w = 0; w < nblk; w++) tsum += ws_sump[(size_t)row * NBLKMAX + w];
  const float logS = logf(tsum);

  // ---- init LDS + segment prefix ----
  for (int i = tid; i < BITWORDS; i += NTB) sh_bitmap[i] = 0u;
  for (int i = tid; i < HASHSZ;   i += NTB) sh_hash[i] = HASH_EMPTY;
  if (tid < 32) { sh_cand_s[tid] = 0ull; sh_sort_s[tid] = 0ull; }  // n==0 parity
  if (tid == 0) {
    sh_cut = 0;
    int acc = 0;
    for (int b2 = 0; b2 < nblk; b2++) {
      sh_off[b2] = acc;
      int c = (int)ws_cntp[(size_t)row * NBLKMAX + b2];
      if (c > CAPB) c = CAPB;
      acc += c;
    }
    sh_off[nblk] = acc;
  }
  __syncthreads();

  // ---- gather candidate segments (order canonicalized by rank sort) ----
  const int ntot = sh_off[nblk];
  const int n = (ntot < GCAP) ? ntot : GCAP;
  for (int b2 = 0; b2 < nblk; b2++) {
    int off = sh_off[b2], c = sh_off[b2 + 1] - off;
    for (int i = tid; i < c; i += NTB) {
      int d = off + i;
      if (d < GCAP)
        sh_cand[d] = ws_cand[(size_t)row * (NBLKMAX * CAPB) + (size_t)b2 * CAPB + i];
    }
  }

  // ---- build seen-bitmap + output-count hash ----
  for (int i = tid; i < P; i += NTB) {
    int v = prompt_ids[(size_t)row * P + i];
    atomicOr(&sh_bitmap[v >> 5], 1u << (v & 31));
  }
  for (int i = tid; i < O; i += NTB) {
    if (i < olen) {
      int v = output_ids[(size_t)row * O + i];
      atomicOr(&sh_bitmap[v >> 5], 1u << (v & 31));
      uint32_t h = ((uint32_t)v * 2654435761u) & (HASHSZ - 1);
      for (;;) {
        uint32_t old = atomicCAS(&sh_hash[h], HASH_EMPTY, ((uint32_t)v << 10) | 1u);
        if (old == HASH_EMPTY) break;
        if ((old >> 10) == (uint32_t)v) { atomicAdd(&sh_hash[h], 1u); break; }
        h = (h + 1) & (HASHSZ - 1);
      }
    }
  }
  __syncthreads();

  // ---- penalize candidates, build sort keys ----
  for (int i = tid; i < n; i += NTB) {
    uint64_t c = sh_cand[i];
    float l = funkey((uint32_t)(c >> 32));
    int  v  = (int)(~(uint32_t)c);
    if (penal && (v == s0 || v == s1 || v == s2 || v == s3)) l = NEG_INF_F;
    bool seen = (sh_bitmap[v >> 5] >> (v & 31)) & 1u;
    if (seen) {
      l = (l > 0.0f) ? (l / rep) : (l * rep);
      uint32_t h = ((uint32_t)v * 2654435761u) & (HASHSZ - 1);
      uint32_t cnt = 0;
      for (;;) {
        uint32_t x = sh_hash[h];
        if (x == HASH_EMPTY) break;
        if ((x >> 10) == (uint32_t)v) { cnt = x & 1023u; break; }
        h = (h + 1) & (HASHSZ - 1);
      }
      if (cnt) {
        float t = __fmul_rn(freq, (float)cnt);
        l = __fsub_rn(l, t);
        l = __fsub_rn(l, pres);
      }
    }
    sh_sort[i] = ((uint64_t)fkey(l) << 32) | (uint32_t)(~(uint32_t)v);
  }
  __syncthreads();

  // ---- dual rank-by-counting sort (descending; unique 64-bit values =>
  //      bijective ranks => identical result to full sort) ----
  for (int i = tid; i < n; i += NTB) {
    uint64_t ci = sh_cand[i], si = sh_sort[i];
    int rc = 0, rs = 0;
    for (int j = 0; j < n; j++) {
      rc += (sh_cand[j] > ci);
      rs += (sh_sort[j] > si);
    }
    sh_cand_s[rc] = ci;
    sh_sort_s[rs] = si;
  }
  __syncthreads();

  // ---- top-NL logprobs output (raw) ----
  if (tid < NL && tid < n) {
    uint64_t c = sh_cand_s[tid];
    float val = funkey((uint32_t)(c >> 32));
    int   idx = (int)(~(uint32_t)c);
    out[B + (size_t)row * NL + tid]                  = val - logS;
    out[B + (size_t)B * NL + (size_t)row * NL + tid] = (float)idx;
  }

  // ---- top-k threshold (count of keys >= kth key, with ties) ----
  if (tid == 0) {
    int kk = (k <= n) ? k : n;
    uint32_t tkey = (uint32_t)(sh_sort_s[kk - 1] >> 32);
    int lo = kk, hi = n;
    while (lo < hi) {
      int mid = (lo + hi) >> 1;
      if ((uint32_t)(sh_sort_s[mid] >> 32) >= tkey) lo = mid + 1; else hi = mid;
    }
    sh_s = lo;
  }
  __syncthreads();
  const int s = sh_s;

  // ---- top-p cut (numerics identical to verified version) ----
  const float g0 = funkey((uint32_t)(sh_sort_s[0] >> 32)) / temp_eff;
  for (int i = tid; i < s; i += NTB) {
    float gi = funkey((uint32_t)(sh_sort_s[i] >> 32)) / temp_eff;
    sh_eval[i] = expf(gi - g0);
  }
  __syncthreads();
  const float thresh = 1.0f - topp;
  for (int i = tid; i < s; i += NTB) {
    float Z = 0.0f;
    for (int t2 = s - 1; t2 >= 0; t2--) Z += sh_eval[t2];
    float suf = 0.0f;
    for (int t2 = s - 1; t2 >= i; t2--) suf += sh_eval[t2] / Z;
    if (suf <= thresh) atomicAdd(&sh_cut, 1);
  }
  __syncthreads();
  int jcut = sh_cut; if (jcut > s - 1) jcut = s - 1;
  const int sfin = s - jcut;

  // ---- gumbel argmax over surviving candidates ----
  float best = -__builtin_inff(); int bestIdx = 0x7FFFFFFF;
  for (int i = tid; i < sfin; i += NTB) {
    uint64_t c = sh_sort_s[i];
    int v = (int)(~(uint32_t)c);
    float gi = funkey((uint32_t)(c >> 32)) / temp_eff;
    float tot = gi + gumbel_at((uint64_t)row * (uint64_t)V + (uint64_t)v);
    if (tot > best || (tot == best && v < bestIdx)) { best = tot; bestIdx = v; }
  }
  for (int off = 1; off < 64; off <<= 1) {
    float bo = __shfl_xor(best, off);
    int   io = __shfl_xor(bestIdx, off);
    if (bo > best || (bo == best && io < bestIdx)) { best = bo; bestIdx = io; }
  }
  if ((tid & 63) == 0) { sh_redm[tid >> 6] = best; sh_redi[tid >> 6] = bestIdx; }
  __syncthreads();
  if (tid == 0) {
    float bb = sh_redm[0]; int bi = sh_redi[0];
    for (int w = 1; w < NTB / 64; w++) {
      float bo = sh_redm[w]; int io = sh_redi[w];
      if (bo > bb || (bo == bb && io < bi)) { bb = bo; bi = io; }
    }
    int greedy = (int)(~(uint32_t)sh_sort_s[0]);
    int sampled = (temp < 1e-5f) ? greedy : bi;
    out[row] = (float)sampled;
  }
}

extern "C" void kernel_launch(void* const* d_in, const int* in_sizes, int n_in,
                              void* d_out, int out_size, void* d_ws, size_t ws_size,
                              hipStream_t stream) {
  const float* logits      = (const float*)d_in[0];
  const float* temperature = (const float*)d_in[1];
  const float* presence    = (const float*)d_in[2];
  const float* frequency   = (const float*)d_in[3];
  const float* repetition  = (const float*)d_in[4];
  const float* top_p       = (const float*)d_in[5];
  const int*   prompt_ids  = (const int*)d_in[6];
  const int*   output_ids  = (const int*)d_in[7];
  const int*   output_lens = (const int*)d_in[8];
  const int*   stop_ids    = (const int*)d_in[9];
  const int*   min_tokens  = (const int*)d_in[10];
  const int*   top_k       = (const int*)d_in[11];
  float* out = (float*)d_out;

  const int B  = in_sizes[1];
  const int V  = in_sizes[0] / B;
  const int P  = in_sizes[6] / B;
  const int O  = in_sizes[7] / B;
  const int S  = in_sizes[9] / B;
  const int NL = (out_size / B - 1) / 2;

  // ws layout (every slot written by K1 before K2 reads -> NO zeroing):
  //   cntp(u32 x B x 32) @0 | sump(f32 x B x 32) @16K | cand(u64 x B x 32*128) @32K
  uint32_t* ws_cntp = (uint32_t*)d_ws;
  float*    ws_sump = (float*)((char*)d_ws + (size_t)B * NBLKMAX * 4);
  uint64_t* ws_cand = (uint64_t*)((char*)d_ws + (size_t)2 * B * NBLKMAX * 4);

  const int nv4 = V >> 2;
  const int nblk = (nv4 + CHUNK4 - 1) / CHUNK4;   // 16 for V=128000
  dim3 grid(nblk, B);
  if (V == 128000) {
    stream_kernel<32000><<<grid, NTA, 0, stream>>>(logits, ws_cntp, ws_sump, ws_cand, V, nv4);
  } else {
    stream_kernel<0><<<grid, NTA, 0, stream>>>(logits, ws_cntp, ws_sump, ws_cand, V, nv4);
  }
  finalize_kernel<<<B, NTB, 0, stream>>>(
      temperature, presence, frequency, repetition, top_p,
      prompt_ids, output_ids, output_lens, stop_ids, min_tokens, top_k,
      ws_cntp, ws_sump, ws_cand, out, B, V, P, O, S, NL, nblk);
}

// Round 13
// 131.145 us; speedup vs baseline: 1.0165x; 1.0165x over previous
//
#include <hip/hip_runtime.h>
#include <stdint.h>

// Sampler_6107443495068 — vLLM-style sampler on MI355X (gfx950).
// R17 post-mortem: split total 133.3 vs fused 130. Found config bug:
//   waves_per_eu(4,4) on K1 CAPS occupancy at 4 waves/EU -> only 4 blocks/CU
//   resident (half of m13's 6.3 TB/s config: 256-thr, 8 blk/CU, 32 waves/CU,
//   low-ILP high-TLP). K2 also has ~6 µs of serial dependent global loads
//   (tid==0 prefix + tsum chains).
// R18 (this round): (1) K1 -> m13 shape: no waves cap, 2-live-float4
//   pipeline (~40 VGPR, fits default 64-VGPR/8-waves-EU target, no spill)
//   -> 8 blocks/CU, latency hidden by TLP. (2) K2: batch prefix/tsum loads
//   into registers (independent -> 1 latency), reduce in IDENTICAL serial
//   order (bit-exact logS); flat gather (1 strided round, segment lookup in
//   LDS). Predict: K1 10-14 µs @ 4.5-6.5 TB/s Occ>=80%, K2 9-13, total
//   120-127. No improvement below 130 -> split path exhausted.
// RNG: exact JAX threefry2x32 partitionable (bits = x0^x1), key 42.

#define NTA      256                 // K1 threads
#define SLOTS_K1 8                   // float4 per K1 thread
#define CHUNK4   (NTA * SLOTS_K1)    // 2048 float4 per block
#define CAPB     128                 // per-block candidate segment cap
#define NBLKMAX  32                  // segment slots per row in ws
#define NTB      512                 // K2 threads
#define GCAP     1024                // per-row candidate cap in K2
#define BITWORDS 4000                // 128000 / 32
#define HASHSZ   1024
#define CUTF     3.0f                // candidate cutoff (== fkey 0xC0400000)
#define HASH_EMPTY 0xFFFFFFFFu
#define NEG_INF_F -3.402823466e38f   // jnp.finfo(f32).min
#define PADV     -1.0e30f

__device__ __forceinline__ uint32_t fkey(float f) {
  uint32_t u = __float_as_uint(f);
  return (u & 0x80000000u) ? ~u : (u | 0x80000000u);
}
__device__ __forceinline__ float funkey(uint32_t k) {
  uint32_t u = (k & 0x80000000u) ? (k & 0x7FFFFFFFu) : ~k;
  return __uint_as_float(u);
}

__device__ __forceinline__ void threefry(uint32_t x0, uint32_t x1,
                                         uint32_t &o0, uint32_t &o1) {
  const uint32_t ks0 = 0u, ks1 = 42u, ks2 = 0u ^ 42u ^ 0x1BD11BDAu;
  x0 += ks0; x1 += ks1;
#define TF_R(r) { x0 += x1; x1 = (x1 << (r)) | (x1 >> (32 - (r))); x1 ^= x0; }
  TF_R(13) TF_R(15) TF_R(26) TF_R(6)
  x0 += ks1; x1 += ks2 + 1u;
  TF_R(17) TF_R(29) TF_R(16) TF_R(24)
  x0 += ks2; x1 += ks0 + 2u;
  TF_R(13) TF_R(15) TF_R(26) TF_R(6)
  x0 += ks0; x1 += ks1 + 3u;
  TF_R(17) TF_R(29) TF_R(16) TF_R(24)
  x0 += ks1; x1 += ks2 + 4u;
  TF_R(13) TF_R(15) TF_R(26) TF_R(6)
  x0 += ks2; x1 += ks0 + 5u;
#undef TF_R
  o0 = x0; o1 = x1;
}

__device__ __forceinline__ float gumbel_at(uint64_t flat) {
  uint32_t o0, o1;
  threefry((uint32_t)(flat >> 32), (uint32_t)flat, o0, o1);
  uint32_t bits = o0 ^ o1;
  float f = __uint_as_float((bits >> 9) | 0x3F800000u) - 1.0f;  // [0,1)
  float u = fmaxf(1e-10f, f + 1e-10f);
  return -logf(-logf(u));
}

// ---------------- K1: stream logits (m13-shaped: 8 blk/CU, TLP) -----------
template<int CNV4>
__global__ __launch_bounds__(NTA)    // no waves cap: default 8 waves/EU target
void stream_kernel(const float* __restrict__ logits,
                   uint32_t* __restrict__ ws_cntp,
                   float* __restrict__ ws_sump,
                   uint64_t* __restrict__ ws_cand,
                   int V, int nv4_arg)
{
  const int row = blockIdx.y;
  const int bx  = blockIdx.x;
  const int nv4 = (CNV4 > 0) ? CNV4 : nv4_arg;
  const int i0 = bx * CHUNK4 + threadIdx.x;
  const int t = threadIdx.x;
  const float4* lg4 = (const float4*)(logits + (size_t)row * V);

  __shared__ uint64_t sh_buf[CAPB];
  __shared__ uint32_t sh_cnt;
  __shared__ float    sh_ws[NTA / 64];
  if (t == 0) sh_cnt = 0u;
  __syncthreads();

  auto ld = [&](int slot) -> float4 {
    int idx = i0 + slot * NTA;
    return (idx < nv4) ? lg4[idx] : make_float4(PADV, PADV, PADV, PADV);
  };

  float sa = 0.f, sb = 0.f, sc = 0.f, sd = 0.f;

  // 2-live-buffer stream: minimal VGPR; latency hidden by 32 waves/CU TLP
  float4 cur = ld(0);
#pragma unroll
  for (int s = 0; s < SLOTS_K1; s++) {
    float4 nxt = (s + 1 < SLOTS_K1) ? ld(s + 1)
                                    : make_float4(PADV, PADV, PADV, PADV);
    float4 f = cur;
    sa += __expf(f.x); sb += __expf(f.y);
    sc += __expf(f.z); sd += __expf(f.w);
    bool c0 = f.x >= CUTF, c1 = f.y >= CUTF, c2 = f.z >= CUTF, c3 = f.w >= CUTF;
    if (__any(c0 | c1 | c2 | c3)) {
      int vb = (i0 + s * NTA) << 2;
      if (c0) { uint32_t sl = atomicAdd(&sh_cnt, 1u); if (sl < CAPB) sh_buf[sl] = ((uint64_t)fkey(f.x) << 32) | (uint32_t)(~(uint32_t)(vb + 0)); }
      if (c1) { uint32_t sl = atomicAdd(&sh_cnt, 1u); if (sl < CAPB) sh_buf[sl] = ((uint64_t)fkey(f.y) << 32) | (uint32_t)(~(uint32_t)(vb + 1)); }
      if (c2) { uint32_t sl = atomicAdd(&sh_cnt, 1u); if (sl < CAPB) sh_buf[sl] = ((uint64_t)fkey(f.z) << 32) | (uint32_t)(~(uint32_t)(vb + 2)); }
      if (c3) { uint32_t sl = atomicAdd(&sh_cnt, 1u); if (sl < CAPB) sh_buf[sl] = ((uint64_t)fkey(f.w) << 32) | (uint32_t)(~(uint32_t)(vb + 3)); }
    }
    cur = nxt;
  }

  // block exp-sum (deterministic order)
  float s = (sa + sb) + (sc + sd);
  for (int off = 1; off < 64; off <<= 1) s += __shfl_xor(s, off);
  if ((t & 63) == 0) sh_ws[t >> 6] = s;
  __syncthreads();

  if (t == 0) {
    float tt = 0.f;
    for (int w = 0; w < NTA / 64; w++) tt += sh_ws[w];
    ws_sump[(size_t)row * NBLKMAX + bx] = tt;       // private slot, no atomic
    uint32_t cnt = (sh_cnt < CAPB) ? sh_cnt : CAPB;
    ws_cntp[(size_t)row * NBLKMAX + bx] = cnt;      // private slot, no atomic
  }
  __syncthreads();

  // flush candidates to private segment (coalesced)
  uint32_t cnt = (sh_cnt < CAPB) ? sh_cnt : CAPB;
  uint64_t segbase = (size_t)row * (NBLKMAX * CAPB) + (size_t)bx * CAPB;
  for (uint32_t i = t; i < cnt; i += NTA)
    ws_cand[segbase + i] = sh_buf[i];
}

// ---------------- K2: finalize per row (rank sort; batched chains) --------
__global__ __launch_bounds__(NTB)
__attribute__((amdgpu_waves_per_eu(2, 2)))
void finalize_kernel(const float* __restrict__ temperature,
                     const float* __restrict__ presence,
                     const float* __restrict__ frequency,
                     const float* __restrict__ repetition,
                     const float* __restrict__ top_p,
                     const int* __restrict__ prompt_ids,
                     const int* __restrict__ output_ids,
                     const int* __restrict__ output_lens,
                     const int* __restrict__ stop_ids,
                     const int* __restrict__ min_tokens,
                     const int* __restrict__ top_k,
                     const uint32_t* __restrict__ ws_cntp,
                     const float* __restrict__ ws_sump,
                     const uint64_t* __restrict__ ws_cand,
                     float* __restrict__ out,
                     int B, int V, int P, int O, int S, int NL, int nblk)
{
  __shared__ uint32_t sh_bitmap[BITWORDS];   // 16000 B
  __shared__ uint32_t sh_hash[HASHSZ];       //  4096 B
  __shared__ uint64_t sh_cand[GCAP];         //  8192 B (unsorted raw)
  __shared__ uint64_t sh_sort[GCAP];         //  8192 B (unsorted penalized)
  __shared__ uint64_t sh_cand_s[GCAP];       //  8192 B (rank-sorted raw)
  __shared__ uint64_t sh_sort_s[GCAP];       //  8192 B (rank-sorted penalized)
  __shared__ float    sh_eval[GCAP];         //  4096 B
  __shared__ float    sh_redm[NTB / 64];
  __shared__ int      sh_redi[NTB / 64];
  __shared__ int      sh_off[NBLKMAX + 1];
  __shared__ float    sh_total;
  __shared__ int      sh_s, sh_cut;

  const int row = blockIdx.x;
  const int tid = threadIdx.x;

  const float temp = temperature[row];
  const float pres = presence[row];
  const float freq = frequency[row];
  const float rep  = repetition[row];
  const float topp = top_p[row];
  const int   olen = output_lens[row];
  const int   mint = min_tokens[row];
  int k = top_k[row]; if (k < 1) k = 1; if (k > V) k = V;
  const bool  penal = olen < mint;
  const int   s0 = stop_ids[row*S + 0], s1 = stop_ids[row*S + 1];
  const int   s2 = stop_ids[row*S + 2], s3 = stop_ids[row*S + 3];
  const float temp_eff = (temp < 1e-5f) ? 1.0f : temp;

  // ---- init LDS; batched prefix + tsum (independent loads -> 1 latency,
  //      then reduce in the SAME serial order as before => bit-exact) ----
  for (int i = tid; i < BITWORDS; i += NTB) sh_bitmap[i] = 0u;
  for (int i = tid; i < HASHSZ;   i += NTB) sh_hash[i] = HASH_EMPTY;
  if (tid < 32) { sh_cand_s[tid] = 0ull; sh_sort_s[tid] = 0ull; }  // n==0 parity
  if (tid == 0) {
    sh_cut = 0;
    uint32_t carr[NBLKMAX];
    float    sarr[NBLKMAX];
#pragma unroll
    for (int b2 = 0; b2 < NBLKMAX; b2++) {   // static idx: stays in registers
      carr[b2] = (b2 < nblk) ? ws_cntp[(size_t)row * NBLKMAX + b2] : 0u;
      sarr[b2] = (b2 < nblk) ? ws_sump[(size_t)row * NBLKMAX + b2] : 0.0f;
    }
    int acc = 0; float ts = 0.f;
#pragma unroll
    for (int b2 = 0; b2 < NBLKMAX; b2++) {
      if (b2 <= nblk) sh_off[b2] = acc;      // sh_off[b2] = prefix before b2
      int c = (int)carr[b2]; if (c > CAPB) c = CAPB;
      acc += (b2 < nblk) ? c : 0;
      ts  += sarr[b2];                       // +0.0 beyond nblk: exact
    }
    sh_off[nblk] = acc;
    sh_total = ts;
  }
  __syncthreads();
  const float logS = logf(sh_total);

  // ---- flat gather (one strided round; segment lookup in LDS) ----
  const int ntot = sh_off[nblk];
  const int n = (ntot < GCAP) ? ntot : GCAP;
  for (int d = tid; d < n; d += NTB) {
    int b2 = 0;
    while (sh_off[b2 + 1] <= d) b2++;        // <= nblk iters, LDS reads
    int i = d - sh_off[b2];
    sh_cand[d] = ws_cand[(size_t)row * (NBLKMAX * CAPB) + (size_t)b2 * CAPB + i];
  }

  // ---- build seen-bitmap + output-count hash ----
  for (int i = tid; i < P; i += NTB) {
    int v = prompt_ids[(size_t)row * P + i];
    atomicOr(&sh_bitmap[v >> 5], 1u << (v & 31));
  }
  for (int i = tid; i < O; i += NTB) {
    if (i < olen) {
      int v = output_ids[(size_t)row * O + i];
      atomicOr(&sh_bitmap[v >> 5], 1u << (v & 31));
      uint32_t h = ((uint32_t)v * 2654435761u) & (HASHSZ - 1);
      for (;;) {
        uint32_t old = atomicCAS(&sh_hash[h], HASH_EMPTY, ((uint32_t)v << 10) | 1u);
        if (old == HASH_EMPTY) break;
        if ((old >> 10) == (uint32_t)v) { atomicAdd(&sh_hash[h], 1u); break; }
        h = (h + 1) & (HASHSZ - 1);
      }
    }
  }
  __syncthreads();

  // ---- penalize candidates, build sort keys ----
  for (int i = tid; i < n; i += NTB) {
    uint64_t c = sh_cand[i];
    float l = funkey((uint32_t)(c >> 32));
    int  v  = (int)(~(uint32_t)c);
    if (penal && (v == s0 || v == s1 || v == s2 || v == s3)) l = NEG_INF_F;
    bool seen = (sh_bitmap[v >> 5] >> (v & 31)) & 1u;
    if (seen) {
      l = (l > 0.0f) ? (l / rep) : (l * rep);
      uint32_t h = ((uint32_t)v * 2654435761u) & (HASHSZ - 1);
      uint32_t cnt = 0;
      for (;;) {
        uint32_t x = sh_hash[h];
        if (x == HASH_EMPTY) break;
        if ((x >> 10) == (uint32_t)v) { cnt = x & 1023u; break; }
        h = (h + 1) & (HASHSZ - 1);
      }
      if (cnt) {
        float t = __fmul_rn(freq, (float)cnt);
        l = __fsub_rn(l, t);
        l = __fsub_rn(l, pres);
      }
    }
    sh_sort[i] = ((uint64_t)fkey(l) << 32) | (uint32_t)(~(uint32_t)v);
  }
  __syncthreads();

  // ---- dual rank-by-counting sort (descending; unique 64-bit values =>
  //      bijective ranks => identical result to full sort) ----
  for (int i = tid; i < n; i += NTB) {
    uint64_t ci = sh_cand[i], si = sh_sort[i];
    int rc = 0, rs = 0;
    for (int j = 0; j < n; j++) {
      rc += (sh_cand[j] > ci);
      rs += (sh_sort[j] > si);
    }
    sh_cand_s[rc] = ci;
    sh_sort_s[rs] = si;
  }
  __syncthreads();

  // ---- top-NL logprobs output (raw) ----
  if (tid < NL && tid < n) {
    uint64_t c = sh_cand_s[tid];
    float val = funkey((uint32_t)(c >> 32));
    int   idx = (int)(~(uint32_t)c);
    out[B + (size_t)row * NL + tid]                  = val - logS;
    out[B + (size_t)B * NL + (size_t)row * NL + tid] = (float)idx;
  }

  // ---- top-k threshold (count of keys >= kth key, with ties) ----
  if (tid == 0) {
    int kk = (k <= n) ? k : n;
    uint32_t tkey = (uint32_t)(sh_sort_s[kk - 1] >> 32);
    int lo = kk, hi = n;
    while (lo < hi) {
      int mid = (lo + hi) >> 1;
      if ((uint32_t)(sh_sort_s[mid] >> 32) >= tkey) lo = mid + 1; else hi = mid;
    }
    sh_s = lo;
  }
  __syncthreads();
  const int s = sh_s;

  // ---- top-p cut (numerics identical to verified version) ----
  const float g0 = funkey((uint32_t)(sh_sort_s[0] >> 32)) / temp_eff;
  for (int i = tid; i < s; i += NTB) {
    float gi = funkey((uint32_t)(sh_sort_s[i] >> 32)) / temp_eff;
    sh_eval[i] = expf(gi - g0);
  }
  __syncthreads();
  const float thresh = 1.0f - topp;
  for (int i = tid; i < s; i += NTB) {
    float Z = 0.0f;
    for (int t2 = s - 1; t2 >= 0; t2--) Z += sh_eval[t2];
    float suf = 0.0f;
    for (int t2 = s - 1; t2 >= i; t2--) suf += sh_eval[t2] / Z;
    if (suf <= thresh) atomicAdd(&sh_cut, 1);
  }
  __syncthreads();
  int jcut = sh_cut; if (jcut > s - 1) jcut = s - 1;
  const int sfin = s - jcut;

  // ---- gumbel argmax over surviving candidates ----
  float best = -__builtin_inff(); int bestIdx = 0x7FFFFFFF;
  for (int i = tid; i < sfin; i += NTB) {
    uint64_t c = sh_sort_s[i];
    int v = (int)(~(uint32_t)c);
    float gi = funkey((uint32_t)(c >> 32)) / temp_eff;
    float tot = gi + gumbel_at((uint64_t)row * (uint64_t)V + (uint64_t)v);
    if (tot > best || (tot == best && v < bestIdx)) { best = tot; bestIdx = v; }
  }
  for (int off = 1; off < 64; off <<= 1) {
    float bo = __shfl_xor(best, off);
    int   io = __shfl_xor(bestIdx, off);
    if (bo > best || (bo == best && io < bestIdx)) { best = bo; bestIdx = io; }
  }
  if ((tid & 63) == 0) { sh_redm[tid >> 6] = best; sh_redi[tid >> 6] = bestIdx; }
  __syncthreads();
  if (tid == 0) {
    float bb = sh_redm[0]; int bi = sh_redi[0];
    for (int w = 1; w < NTB / 64; w++) {
      float bo = sh_redm[w]; int io = sh_redi[w];
      if (bo > bb || (bo == bb && io < bi)) { bb = bo; bi = io; }
    }
    int greedy = (int)(~(uint32_t)sh_sort_s[0]);
    int sampled = (temp < 1e-5f) ? greedy : bi;
    out[row] = (float)sampled;
  }
}

extern "C" void kernel_launch(void* const* d_in, const int* in_sizes, int n_in,
                              void* d_out, int out_size, void* d_ws, size_t ws_size,
                              hipStream_t stream) {
  const float* logits      = (const float*)d_in[0];
  const float* temperature = (const float*)d_in[1];
  const float* presence    = (const float*)d_in[2];
  const float* frequency   = (const float*)d_in[3];
  const float* repetition  = (const float*)d_in[4];
  const float* top_p       = (const float*)d_in[5];
  const int*   prompt_ids  = (const int*)d_in[6];
  const int*   output_ids  = (const int*)d_in[7];
  const int*   output_lens = (const int*)d_in[8];
  const int*   stop_ids    = (const int*)d_in[9];
  const int*   min_tokens  = (const int*)d_in[10];
  const int*   top_k       = (const int*)d_in[11];
  float* out = (float*)d_out;

  const int B  = in_sizes[1];
  const int V  = in_sizes[0] / B;
  const int P  = in_sizes[6] / B;
  const int O  = in_sizes[7] / B;
  const int S  = in_sizes[9] / B;
  const int NL = (out_size / B - 1) / 2;

  // ws layout (every slot written by K1 before K2 reads -> NO zeroing):
  //   cntp(u32 x B x 32) @0 | sump(f32 x B x 32) @16K | cand(u64 x B x 32*128) @32K
  uint32_t* ws_cntp = (uint32_t*)d_ws;
  float*    ws_sump = (float*)((char*)d_ws + (size_t)B * NBLKMAX * 4);
  uint64_t* ws_cand = (uint64_t*)((char*)d_ws + (size_t)2 * B * NBLKMAX * 4);

  const int nv4 = V >> 2;
  const int nblk = (nv4 + CHUNK4 - 1) / CHUNK4;   // 16 for V=128000
  dim3 grid(nblk, B);
  if (V == 128000) {
    stream_kernel<32000><<<grid, NTA, 0, stream>>>(logits, ws_cntp, ws_sump, ws_cand, V, nv4);
  } else {
    stream_kernel<0><<<grid, NTA, 0, stream>>>(logits, ws_cntp, ws_sump, ws_cand, V, nv4);
  }
  finalize_kernel<<<B, NTB, 0, stream>>>(
      temperature, presence, frequency, repetition, top_p,
      prompt_ids, output_ids, output_lens, stop_ids, min_tokens, top_k,
      ws_cntp, ws_sump, ws_cand, out, B, V, P, O, S, NL, nblk);
}

// Round 14
// 129.290 us; speedup vs baseline: 1.0311x; 1.0144x over previous
//
#include <hip/hip_runtime.h>
#include <stdint.h>

// Sampler_6107443495068 — vLLM-style sampler on MI355X (gfx950).
// R18 post-mortem: occupancy-fixed split = 131.1, tied with fused 130.0.
//   K1+K2+gap ≈ 39 µs, composition opaque (both kernels below top-5 fill
//   cutoff). Theoretical floor ≈ 92 fixed + 11 stream + 5 gap + 8 finalize
//   = ~116.
// R19 (this round): last two independent knobs.
//   K1: SLOTS 8->4, 32 blk/row = 4096 blocks (16384 waves, 2x oversub) —
//       queue depth for the memory system + smaller tail imbalance.
//   K2: NTB 512->1024 (2x TLP in every latency-bound phase), no waves cap.
//   Predict: total 122-126 if the residual was K1-or-K2; >=129 -> declare
//   structural floor (fused 130.0 best) next round.
// RNG: exact JAX threefry2x32 partitionable (bits = x0^x1), key 42.

#define NTA      256                 // K1 threads
#define SLOTS_K1 4                   // float4 per K1 thread
#define CHUNK4   (NTA * SLOTS_K1)    // 1024 float4 per block
#define CAPB     128                 // per-block candidate segment cap
#define NBLKMAX  32                  // segment slots per row in ws
#define NTB      1024                // K2 threads
#define GCAP     1024                // per-row candidate cap in K2
#define BITWORDS 4000                // 128000 / 32
#define HASHSZ   1024
#define CUTF     3.0f                // candidate cutoff (== fkey 0xC0400000)
#define HASH_EMPTY 0xFFFFFFFFu
#define NEG_INF_F -3.402823466e38f   // jnp.finfo(f32).min
#define PADV     -1.0e30f

__device__ __forceinline__ uint32_t fkey(float f) {
  uint32_t u = __float_as_uint(f);
  return (u & 0x80000000u) ? ~u : (u | 0x80000000u);
}
__device__ __forceinline__ float funkey(uint32_t k) {
  uint32_t u = (k & 0x80000000u) ? (k & 0x7FFFFFFFu) : ~k;
  return __uint_as_float(u);
}

__device__ __forceinline__ void threefry(uint32_t x0, uint32_t x1,
                                         uint32_t &o0, uint32_t &o1) {
  const uint32_t ks0 = 0u, ks1 = 42u, ks2 = 0u ^ 42u ^ 0x1BD11BDAu;
  x0 += ks0; x1 += ks1;
#define TF_R(r) { x0 += x1; x1 = (x1 << (r)) | (x1 >> (32 - (r))); x1 ^= x0; }
  TF_R(13) TF_R(15) TF_R(26) TF_R(6)
  x0 += ks1; x1 += ks2 + 1u;
  TF_R(17) TF_R(29) TF_R(16) TF_R(24)
  x0 += ks2; x1 += ks0 + 2u;
  TF_R(13) TF_R(15) TF_R(26) TF_R(6)
  x0 += ks0; x1 += ks1 + 3u;
  TF_R(17) TF_R(29) TF_R(16) TF_R(24)
  x0 += ks1; x1 += ks2 + 4u;
  TF_R(13) TF_R(15) TF_R(26) TF_R(6)
  x0 += ks2; x1 += ks0 + 5u;
#undef TF_R
  o0 = x0; o1 = x1;
}

__device__ __forceinline__ float gumbel_at(uint64_t flat) {
  uint32_t o0, o1;
  threefry((uint32_t)(flat >> 32), (uint32_t)flat, o0, o1);
  uint32_t bits = o0 ^ o1;
  float f = __uint_as_float((bits >> 9) | 0x3F800000u) - 1.0f;  // [0,1)
  float u = fmaxf(1e-10f, f + 1e-10f);
  return -logf(-logf(u));
}

// ---------------- K1: stream logits (2x oversubscribed, TLP) --------------
template<int CNV4>
__global__ __launch_bounds__(NTA)    // default reg target; ~2-buf pipeline
void stream_kernel(const float* __restrict__ logits,
                   uint32_t* __restrict__ ws_cntp,
                   float* __restrict__ ws_sump,
                   uint64_t* __restrict__ ws_cand,
                   int V, int nv4_arg)
{
  const int row = blockIdx.y;
  const int bx  = blockIdx.x;
  const int nv4 = (CNV4 > 0) ? CNV4 : nv4_arg;
  const int i0 = bx * CHUNK4 + threadIdx.x;
  const int t = threadIdx.x;
  const float4* lg4 = (const float4*)(logits + (size_t)row * V);

  __shared__ uint64_t sh_buf[CAPB];
  __shared__ uint32_t sh_cnt;
  __shared__ float    sh_ws[NTA / 64];
  if (t == 0) sh_cnt = 0u;
  __syncthreads();

  auto ld = [&](int slot) -> float4 {
    int idx = i0 + slot * NTA;
    return (idx < nv4) ? lg4[idx] : make_float4(PADV, PADV, PADV, PADV);
  };

  float sa = 0.f, sb = 0.f, sc = 0.f, sd = 0.f;

  // 2-live-buffer stream: minimal VGPR; latency hidden by TLP
  float4 cur = ld(0);
#pragma unroll
  for (int s = 0; s < SLOTS_K1; s++) {
    float4 nxt = (s + 1 < SLOTS_K1) ? ld(s + 1)
                                    : make_float4(PADV, PADV, PADV, PADV);
    float4 f = cur;
    sa += __expf(f.x); sb += __expf(f.y);
    sc += __expf(f.z); sd += __expf(f.w);
    bool c0 = f.x >= CUTF, c1 = f.y >= CUTF, c2 = f.z >= CUTF, c3 = f.w >= CUTF;
    if (__any(c0 | c1 | c2 | c3)) {
      int vb = (i0 + s * NTA) << 2;
      if (c0) { uint32_t sl = atomicAdd(&sh_cnt, 1u); if (sl < CAPB) sh_buf[sl] = ((uint64_t)fkey(f.x) << 32) | (uint32_t)(~(uint32_t)(vb + 0)); }
      if (c1) { uint32_t sl = atomicAdd(&sh_cnt, 1u); if (sl < CAPB) sh_buf[sl] = ((uint64_t)fkey(f.y) << 32) | (uint32_t)(~(uint32_t)(vb + 1)); }
      if (c2) { uint32_t sl = atomicAdd(&sh_cnt, 1u); if (sl < CAPB) sh_buf[sl] = ((uint64_t)fkey(f.z) << 32) | (uint32_t)(~(uint32_t)(vb + 2)); }
      if (c3) { uint32_t sl = atomicAdd(&sh_cnt, 1u); if (sl < CAPB) sh_buf[sl] = ((uint64_t)fkey(f.w) << 32) | (uint32_t)(~(uint32_t)(vb + 3)); }
    }
    cur = nxt;
  }

  // block exp-sum (deterministic order)
  float s = (sa + sb) + (sc + sd);
  for (int off = 1; off < 64; off <<= 1) s += __shfl_xor(s, off);
  if ((t & 63) == 0) sh_ws[t >> 6] = s;
  __syncthreads();

  if (t == 0) {
    float tt = 0.f;
    for (int w = 0; w < NTA / 64; w++) tt += sh_ws[w];
    ws_sump[(size_t)row * NBLKMAX + bx] = tt;       // private slot, no atomic
    uint32_t cnt = (sh_cnt < CAPB) ? sh_cnt : CAPB;
    ws_cntp[(size_t)row * NBLKMAX + bx] = cnt;      // private slot, no atomic
  }
  __syncthreads();

  // flush candidates to private segment (coalesced)
  uint32_t cnt = (sh_cnt < CAPB) ? sh_cnt : CAPB;
  uint64_t segbase = (size_t)row * (NBLKMAX * CAPB) + (size_t)bx * CAPB;
  for (uint32_t i = t; i < cnt; i += NTA)
    ws_cand[segbase + i] = sh_buf[i];
}

// ---------------- K2: finalize per row (rank sort; wide TLP) --------------
__global__ __launch_bounds__(NTB)
void finalize_kernel(const float* __restrict__ temperature,
                     const float* __restrict__ presence,
                     const float* __restrict__ frequency,
                     const float* __restrict__ repetition,
                     const float* __restrict__ top_p,
                     const int* __restrict__ prompt_ids,
                     const int* __restrict__ output_ids,
                     const int* __restrict__ output_lens,
                     const int* __restrict__ stop_ids,
                     const int* __restrict__ min_tokens,
                     const int* __restrict__ top_k,
                     const uint32_t* __restrict__ ws_cntp,
                     const float* __restrict__ ws_sump,
                     const uint64_t* __restrict__ ws_cand,
                     float* __restrict__ out,
                     int B, int V, int P, int O, int S, int NL, int nblk)
{
  __shared__ uint32_t sh_bitmap[BITWORDS];   // 16000 B
  __shared__ uint32_t sh_hash[HASHSZ];       //  4096 B
  __shared__ uint64_t sh_cand[GCAP];         //  8192 B (unsorted raw)
  __shared__ uint64_t sh_sort[GCAP];         //  8192 B (unsorted penalized)
  __shared__ uint64_t sh_cand_s[GCAP];       //  8192 B (rank-sorted raw)
  __shared__ uint64_t sh_sort_s[GCAP];       //  8192 B (rank-sorted penalized)
  __shared__ float    sh_eval[GCAP];         //  4096 B
  __shared__ float    sh_redm[NTB / 64];
  __shared__ int      sh_redi[NTB / 64];
  __shared__ int      sh_off[NBLKMAX + 1];
  __shared__ float    sh_total;
  __shared__ int      sh_s, sh_cut;

  const int row = blockIdx.x;
  const int tid = threadIdx.x;

  const float temp = temperature[row];
  const float pres = presence[row];
  const float freq = frequency[row];
  const float rep  = repetition[row];
  const float topp = top_p[row];
  const int   olen = output_lens[row];
  const int   mint = min_tokens[row];
  int k = top_k[row]; if (k < 1) k = 1; if (k > V) k = V;
  const bool  penal = olen < mint;
  const int   s0 = stop_ids[row*S + 0], s1 = stop_ids[row*S + 1];
  const int   s2 = stop_ids[row*S + 2], s3 = stop_ids[row*S + 3];
  const float temp_eff = (temp < 1e-5f) ? 1.0f : temp;

  // ---- init LDS; batched prefix + tsum (independent loads -> 1 latency,
  //      then reduce in the SAME serial order as before => bit-exact) ----
  for (int i = tid; i < BITWORDS; i += NTB) sh_bitmap[i] = 0u;
  for (int i = tid; i < HASHSZ;   i += NTB) sh_hash[i] = HASH_EMPTY;
  if (tid < 32) { sh_cand_s[tid] = 0ull; sh_sort_s[tid] = 0ull; }  // n==0 parity
  if (tid == 0) {
    sh_cut = 0;
    uint32_t carr[NBLKMAX];
    float    sarr[NBLKMAX];
#pragma unroll
    for (int b2 = 0; b2 < NBLKMAX; b2++) {   // static idx: stays in registers
      carr[b2] = (b2 < nblk) ? ws_cntp[(size_t)row * NBLKMAX + b2] : 0u;
      sarr[b2] = (b2 < nblk) ? ws_sump[(size_t)row * NBLKMAX + b2] : 0.0f;
    }
    int acc = 0; float ts = 0.f;
#pragma unroll
    for (int b2 = 0; b2 < NBLKMAX; b2++) {
      if (b2 <= nblk) sh_off[b2] = acc;      // sh_off[b2] = prefix before b2
      int c = (int)carr[b2]; if (c > CAPB) c = CAPB;
      acc += (b2 < nblk) ? c : 0;
      ts  += sarr[b2];                       // +0.0 beyond nblk: exact
    }
    sh_off[nblk] = acc;
    sh_total = ts;
  }
  __syncthreads();
  const float logS = logf(sh_total);

  // ---- flat gather (one strided round; segment lookup in LDS) ----
  const int ntot = sh_off[nblk];
  const int n = (ntot < GCAP) ? ntot : GCAP;
  for (int d = tid; d < n; d += NTB) {
    int b2 = 0;
    while (sh_off[b2 + 1] <= d) b2++;        // <= nblk iters, LDS reads
    int i = d - sh_off[b2];
    sh_cand[d] = ws_cand[(size_t)row * (NBLKMAX * CAPB) + (size_t)b2 * CAPB + i];
  }

  // ---- build seen-bitmap + output-count hash ----
  for (int i = tid; i < P; i += NTB) {
    int v = prompt_ids[(size_t)row * P + i];
    atomicOr(&sh_bitmap[v >> 5], 1u << (v & 31));
  }
  for (int i = tid; i < O; i += NTB) {
    if (i < olen) {
      int v = output_ids[(size_t)row * O + i];
      atomicOr(&sh_bitmap[v >> 5], 1u << (v & 31));
      uint32_t h = ((uint32_t)v * 2654435761u) & (HASHSZ - 1);
      for (;;) {
        uint32_t old = atomicCAS(&sh_hash[h], HASH_EMPTY, ((uint32_t)v << 10) | 1u);
        if (old == HASH_EMPTY) break;
        if ((old >> 10) == (uint32_t)v) { atomicAdd(&sh_hash[h], 1u); break; }
        h = (h + 1) & (HASHSZ - 1);
      }
    }
  }
  __syncthreads();

  // ---- penalize candidates, build sort keys ----
  for (int i = tid; i < n; i += NTB) {
    uint64_t c = sh_cand[i];
    float l = funkey((uint32_t)(c >> 32));
    int  v  = (int)(~(uint32_t)c);
    if (penal && (v == s0 || v == s1 || v == s2 || v == s3)) l = NEG_INF_F;
    bool seen = (sh_bitmap[v >> 5] >> (v & 31)) & 1u;
    if (seen) {
      l = (l > 0.0f) ? (l / rep) : (l * rep);
      uint32_t h = ((uint32_t)v * 2654435761u) & (HASHSZ - 1);
      uint32_t cnt = 0;
      for (;;) {
        uint32_t x = sh_hash[h];
        if (x == HASH_EMPTY) break;
        if ((x >> 10) == (uint32_t)v) { cnt = x & 1023u; break; }
        h = (h + 1) & (HASHSZ - 1);
      }
      if (cnt) {
        float t = __fmul_rn(freq, (float)cnt);
        l = __fsub_rn(l, t);
        l = __fsub_rn(l, pres);
      }
    }
    sh_sort[i] = ((uint64_t)fkey(l) << 32) | (uint32_t)(~(uint32_t)v);
  }
  __syncthreads();

  // ---- dual rank-by-counting sort (descending; unique 64-bit values =>
  //      bijective ranks => identical result to full sort) ----
  for (int i = tid; i < n; i += NTB) {
    uint64_t ci = sh_cand[i], si = sh_sort[i];
    int rc = 0, rs = 0;
    for (int j = 0; j < n; j++) {
      rc += (sh_cand[j] > ci);
      rs += (sh_sort[j] > si);
    }
    sh_cand_s[rc] = ci;
    sh_sort_s[rs] = si;
  }
  __syncthreads();

  // ---- top-NL logprobs output (raw) ----
  if (tid < NL && tid < n) {
    uint64_t c = sh_cand_s[tid];
    float val = funkey((uint32_t)(c >> 32));
    int   idx = (int)(~(uint32_t)c);
    out[B + (size_t)row * NL + tid]                  = val - logS;
    out[B + (size_t)B * NL + (size_t)row * NL + tid] = (float)idx;
  }

  // ---- top-k threshold (count of keys >= kth key, with ties) ----
  if (tid == 0) {
    int kk = (k <= n) ? k : n;
    uint32_t tkey = (uint32_t)(sh_sort_s[kk - 1] >> 32);
    int lo = kk, hi = n;
    while (lo < hi) {
      int mid = (lo + hi) >> 1;
      if ((uint32_t)(sh_sort_s[mid] >> 32) >= tkey) lo = mid + 1; else hi = mid;
    }
    sh_s = lo;
  }
  __syncthreads();
  const int s = sh_s;

  // ---- top-p cut (numerics identical to verified version) ----
  const float g0 = funkey((uint32_t)(sh_sort_s[0] >> 32)) / temp_eff;
  for (int i = tid; i < s; i += NTB) {
    float gi = funkey((uint32_t)(sh_sort_s[i] >> 32)) / temp_eff;
    sh_eval[i] = expf(gi - g0);
  }
  __syncthreads();
  const float thresh = 1.0f - topp;
  for (int i = tid; i < s; i += NTB) {
    float Z = 0.0f;
    for (int t2 = s - 1; t2 >= 0; t2--) Z += sh_eval[t2];
    float suf = 0.0f;
    for (int t2 = s - 1; t2 >= i; t2--) suf += sh_eval[t2] / Z;
    if (suf <= thresh) atomicAdd(&sh_cut, 1);
  }
  __syncthreads();
  int jcut = sh_cut; if (jcut > s - 1) jcut = s - 1;
  const int sfin = s - jcut;

  // ---- gumbel argmax over surviving candidates ----
  float best = -__builtin_inff(); int bestIdx = 0x7FFFFFFF;
  for (int i = tid; i < sfin; i += NTB) {
    uint64_t c = sh_sort_s[i];
    int v = (int)(~(uint32_t)c);
    float gi = funkey((uint32_t)(c >> 32)) / temp_eff;
    float tot = gi + gumbel_at((uint64_t)row * (uint64_t)V + (uint64_t)v);
    if (tot > best || (tot == best && v < bestIdx)) { best = tot; bestIdx = v; }
  }
  for (int off = 1; off < 64; off <<= 1) {
    float bo = __shfl_xor(best, off);
    int   io = __shfl_xor(bestIdx, off);
    if (bo > best || (bo == best && io < bestIdx)) { best = bo; bestIdx = io; }
  }
  if ((tid & 63) == 0) { sh_redm[tid >> 6] = best; sh_redi[tid >> 6] = bestIdx; }
  __syncthreads();
  if (tid == 0) {
    float bb = sh_redm[0]; int bi = sh_redi[0];
    for (int w = 1; w < NTB / 64; w++) {
      float bo = sh_redm[w]; int io = sh_redi[w];
      if (bo > bb || (bo == bb && io < bi)) { bb = bo; bi = io; }
    }
    int greedy = (int)(~(uint32_t)sh_sort_s[0]);
    int sampled = (temp < 1e-5f) ? greedy : bi;
    out[row] = (float)sampled;
  }
}

extern "C" void kernel_launch(void* const* d_in, const int* in_sizes, int n_in,
                              void* d_out, int out_size, void* d_ws, size_t ws_size,
                              hipStream_t stream) {
  const float* logits      = (const float*)d_in[0];
  const float* temperature = (const float*)d_in[1];
  const float* presence    = (const float*)d_in[2];
  const float* frequency   = (const float*)d_in[3];
  const float* repetition  = (const float*)d_in[4];
  const float* top_p       = (const float*)d_in[5];
  const int*   prompt_ids  = (const int*)d_in[6];
  const int*   output_ids  = (const int*)d_in[7];
  const int*   output_lens = (const int*)d_in[8];
  const int*   stop_ids    = (const int*)d_in[9];
  const int*   min_tokens  = (const int*)d_in[10];
  const int*   top_k       = (const int*)d_in[11];
  float* out = (float*)d_out;

  const int B  = in_sizes[1];
  const int V  = in_sizes[0] / B;
  const int P  = in_sizes[6] / B;
  const int O  = in_sizes[7] / B;
  const int S  = in_sizes[9] / B;
  const int NL = (out_size / B - 1) / 2;

  // ws layout (every slot written by K1 before K2 reads -> NO zeroing):
  //   cntp(u32 x B x 32) @0 | sump(f32 x B x 32) @16K | cand(u64 x B x 32*128) @32K
  uint32_t* ws_cntp = (uint32_t*)d_ws;
  float*    ws_sump = (float*)((char*)d_ws + (size_t)B * NBLKMAX * 4);
  uint64_t* ws_cand = (uint64_t*)((char*)d_ws + (size_t)2 * B * NBLKMAX * 4);

  const int nv4 = V >> 2;
  int nblk = (nv4 + CHUNK4 - 1) / CHUNK4;         // 32 for V=128000
  if (nblk > NBLKMAX) nblk = NBLKMAX;             // safety (layout bound)
  dim3 grid(nblk, B);
  if (V == 128000) {
    stream_kernel<32000><<<grid, NTA, 0, stream>>>(logits, ws_cntp, ws_sump, ws_cand, V, nv4);
  } else {
    stream_kernel<0><<<grid, NTA, 0, stream>>>(logits, ws_cntp, ws_sump, ws_cand, V, nv4);
  }
  finalize_kernel<<<B, NTB, 0, stream>>>(
      temperature, presence, frequency, repetition, top_p,
      prompt_ids, output_ids, output_lens, stop_ids, min_tokens, top_k,
      ws_cntp, ws_sump, ws_cand, out, B, V, P, O, S, NL, nblk);
}